// Round 1
// baseline (55.546 us; speedup 1.0000x reference)
//
#include <hip/hip_runtime.h>

// Chamfer loss: B=8, N1=N2=4096, D=3, fp32 in, scalar fp32 out.
// loss = mean_i min_j ||x_i-y_j||^2 + mean_j min_i ||x_i-y_j||^2
// Strategy: brute-force pair sweep (VALU-bound, ~1.9G ops), LDS-broadcast
// of "other" points, uint-bit atomicMin combine, final mean reduce.

namespace {
constexpr int Bc = 8;
constexpr int Nc = 4096;
constexpr int JCHUNK = 512;               // other-points staged per block
constexpr int TPB = 256;
constexpr int TROWS = 2;                  // row points per thread
constexpr int ROWS_PER_BLOCK = TPB * TROWS;   // 512
constexpr int NJCH = Nc / JCHUNK;         // 8
constexpr int NRB  = Nc / ROWS_PER_BLOCK; // 8
constexpr unsigned INF_BITS = 0x7f800000u;
}

// Persistent scratch (re-initialized every call -> deterministic).
__device__ unsigned int g_mins[2 * Bc * Nc];

__global__ __launch_bounds__(TPB) void init_kernel(float* out) {
  int i = blockIdx.x * TPB + threadIdx.x;
  if (i < 2 * Bc * Nc) g_mins[i] = INF_BITS;
  if (i == 0) out[0] = 0.0f;
}

__global__ __launch_bounds__(TPB) void cham_kernel(const float* __restrict__ pred,
                                                   const float* __restrict__ gt) {
  const int bx     = blockIdx.x;        // [0, NRB*NJCH)
  const int rowblk = bx / NJCH;
  const int jblk   = bx % NJCH;
  const int b      = blockIdx.y;
  const int dir    = blockIdx.z;        // 0: rows=pred vs gt; 1: rows=gt vs pred

  const float* rows    = (dir == 0) ? pred : gt;
  const float* others  = (dir == 0) ? gt : pred;
  const float* rowbase = rows   + ((size_t)b * Nc + (size_t)rowblk * ROWS_PER_BLOCK) * 3;
  const float* othbase = others + ((size_t)b * Nc + (size_t)jblk * JCHUNK) * 3;
  unsigned int* minbase = g_mins + ((size_t)dir * Bc + b) * Nc + (size_t)rowblk * ROWS_PER_BLOCK;

  __shared__ __align__(16) float xs[JCHUNK];
  __shared__ __align__(16) float ys[JCHUNK];
  __shared__ __align__(16) float zs[JCHUNK];

  const int t = threadIdx.x;
  // Stage other-chunk as SoA (one-time, L2-hot after first blocks).
  for (int j = t; j < JCHUNK; j += TPB) {
    xs[j] = othbase[3 * j + 0];
    ys[j] = othbase[3 * j + 1];
    zs[j] = othbase[3 * j + 2];
  }
  __syncthreads();

  // Row points in registers.
  float px[TROWS], py[TROWS], pz[TROWS];
  #pragma unroll
  for (int r = 0; r < TROWS; ++r) {
    const float* p = rowbase + (size_t)(t + r * TPB) * 3;
    px[r] = p[0]; py[r] = p[1]; pz[r] = p[2];
  }

  // 4 independent min accumulators per row point (break v_min dep chain).
  float m0[TROWS], m1[TROWS], m2[TROWS], m3[TROWS];
  #pragma unroll
  for (int r = 0; r < TROWS; ++r) {
    m0[r] = m1[r] = m2[r] = m3[r] = __builtin_inff();
  }

  const float4* x4 = (const float4*)xs;
  const float4* y4 = (const float4*)ys;
  const float4* z4 = (const float4*)zs;

  #pragma unroll 2
  for (int q = 0; q < JCHUNK / 4; ++q) {
    const float4 X = x4[q];
    const float4 Y = y4[q];
    const float4 Z = z4[q];
    #pragma unroll
    for (int r = 0; r < TROWS; ++r) {
      float dx, dy, dz, d2;
      dx = px[r] - X.x; dy = py[r] - Y.x; dz = pz[r] - Z.x;
      d2 = dx * dx + dy * dy + dz * dz;  m0[r] = fminf(m0[r], d2);
      dx = px[r] - X.y; dy = py[r] - Y.y; dz = pz[r] - Z.y;
      d2 = dx * dx + dy * dy + dz * dz;  m1[r] = fminf(m1[r], d2);
      dx = px[r] - X.z; dy = py[r] - Y.z; dz = pz[r] - Z.z;
      d2 = dx * dx + dy * dy + dz * dz;  m2[r] = fminf(m2[r], d2);
      dx = px[r] - X.w; dy = py[r] - Y.w; dz = pz[r] - Z.w;
      d2 = dx * dx + dy * dy + dz * dz;  m3[r] = fminf(m3[r], d2);
    }
  }

  #pragma unroll
  for (int r = 0; r < TROWS; ++r) {
    float m = fminf(fminf(m0[r], m1[r]), fminf(m2[r], m3[r]));
    // d2 >= 0 always -> IEEE bits are monotone as unsigned.
    atomicMin(minbase + t + r * TPB, __float_as_uint(m));
  }
}

__global__ __launch_bounds__(TPB) void reduce_kernel(float* __restrict__ out) {
  const int total = 2 * Bc * Nc;
  float s = 0.0f;
  for (int i = blockIdx.x * TPB + threadIdx.x; i < total; i += gridDim.x * TPB)
    s += __uint_as_float(g_mins[i]);
  #pragma unroll
  for (int off = 32; off > 0; off >>= 1) s += __shfl_down(s, off, 64);
  __shared__ float wsum[TPB / 64];
  const int lane = threadIdx.x & 63;
  const int wid  = threadIdx.x >> 6;
  if (lane == 0) wsum[wid] = s;
  __syncthreads();
  if (threadIdx.x == 0) {
    float tot = 0.0f;
    #pragma unroll
    for (int w = 0; w < TPB / 64; ++w) tot += wsum[w];
    // mean over (B*N) for each direction; N1==N2 so one shared scale.
    atomicAdd(out, tot * (1.0f / (float)(Bc * Nc)));
  }
}

extern "C" void kernel_launch(void* const* d_in, const int* in_sizes, int n_in,
                              void* d_out, int out_size, void* d_ws, size_t ws_size,
                              hipStream_t stream) {
  const float* pred = (const float*)d_in[0];
  const float* gt   = (const float*)d_in[1];
  float* out = (float*)d_out;

  init_kernel<<<(2 * Bc * Nc + TPB - 1) / TPB, TPB, 0, stream>>>(out);

  dim3 grid(NRB * NJCH, Bc, 2);   // 64 x 8 x 2 = 1024 blocks
  cham_kernel<<<grid, TPB, 0, stream>>>(pred, gt);

  reduce_kernel<<<64, TPB, 0, stream>>>(out);
}

// Round 2
// 35.644 us; speedup vs baseline: 1.5584x; 1.5584x over previous
//
#include <hip/hip_runtime.h>

// Chamfer loss: B=8, N1=N2=4096, D=3, fp32 in, scalar fp32 out.
// loss = mean_i min_j ||x_i-y_j||^2 + mean_j min_i ||x_i-y_j||^2
// R2: expanded form. Stage other-points as float4 (x,y,z,h=0.5*||y||^2).
//     s_j = h_j - p.y_j  ==> 3 fma per pair;  d2_min = 2*min_j s_j + ||p||^2.
//     TROWS=4 rows/thread amortizes LDS broadcast + loop overhead.

namespace {
constexpr int Bc = 8;
constexpr int Nc = 4096;
constexpr int TPB = 256;
constexpr int TROWS = 4;                      // row points per thread
constexpr int ROWS_PER_BLOCK = TPB * TROWS;   // 1024
constexpr int JCHUNK = 256;                   // other-points staged per block
constexpr int NJCH = Nc / JCHUNK;             // 16
constexpr int NRB  = Nc / ROWS_PER_BLOCK;     // 4
constexpr unsigned INF_BITS = 0x7f800000u;
}

// Persistent scratch (re-initialized every call -> deterministic).
__device__ unsigned int g_mins[2 * Bc * Nc];

__global__ __launch_bounds__(TPB) void init_kernel(float* out) {
  int i = blockIdx.x * TPB + threadIdx.x;
  if (i < 2 * Bc * Nc) g_mins[i] = INF_BITS;
  if (i == 0) out[0] = 0.0f;
}

__global__ __launch_bounds__(TPB) void cham_kernel(const float* __restrict__ pred,
                                                   const float* __restrict__ gt) {
  const int bx     = blockIdx.x;        // [0, NRB*NJCH)
  const int rowblk = bx / NJCH;
  const int jblk   = bx % NJCH;
  const int b      = blockIdx.y;
  const int dir    = blockIdx.z;        // 0: rows=pred vs gt; 1: rows=gt vs pred

  const float* rows    = (dir == 0) ? pred : gt;
  const float* others  = (dir == 0) ? gt : pred;
  const float* rowbase = rows   + ((size_t)b * Nc + (size_t)rowblk * ROWS_PER_BLOCK) * 3;
  const float* othbase = others + ((size_t)b * Nc + (size_t)jblk * JCHUNK) * 3;
  unsigned int* minbase = g_mins + ((size_t)dir * Bc + b) * Nc + (size_t)rowblk * ROWS_PER_BLOCK;

  __shared__ __align__(16) float4 pts[JCHUNK];   // (x, y, z, 0.5*||y||^2)

  const int t = threadIdx.x;
  {
    // One point per thread: load + compute half-norm.
    const float* p = othbase + 3 * t;
    float x = p[0], y = p[1], z = p[2];
    float h = 0.5f * (x * x + y * y + z * z);
    pts[t] = make_float4(x, y, z, h);
  }
  __syncthreads();

  // Row points: negated coords (pure fma chain) + squared norm.
  float nx[TROWS], ny[TROWS], nz[TROWS], p2[TROWS];
  #pragma unroll
  for (int r = 0; r < TROWS; ++r) {
    const float* p = rowbase + (size_t)(t + r * TPB) * 3;
    float x = p[0], y = p[1], z = p[2];
    nx[r] = -x; ny[r] = -y; nz[r] = -z;
    p2[r] = x * x + y * y + z * z;
  }

  // Two min accumulators per row (independent chains; min3 fusion).
  float a0[TROWS], a1[TROWS];
  #pragma unroll
  for (int r = 0; r < TROWS; ++r) a0[r] = a1[r] = __builtin_inff();

  for (int j = 0; j < JCHUNK; j += 4) {
    const float4 P0 = pts[j + 0];
    const float4 P1 = pts[j + 1];
    const float4 P2 = pts[j + 2];
    const float4 P3 = pts[j + 3];
    #pragma unroll
    for (int r = 0; r < TROWS; ++r) {
      float s0 = fmaf(nx[r], P0.x, fmaf(ny[r], P0.y, fmaf(nz[r], P0.z, P0.w)));
      float s1 = fmaf(nx[r], P1.x, fmaf(ny[r], P1.y, fmaf(nz[r], P1.z, P1.w)));
      float s2 = fmaf(nx[r], P2.x, fmaf(ny[r], P2.y, fmaf(nz[r], P2.z, P2.w)));
      float s3 = fmaf(nx[r], P3.x, fmaf(ny[r], P3.y, fmaf(nz[r], P3.z, P3.w)));
      a0[r] = fminf(fminf(s0, s1), a0[r]);   // -> v_min3_f32
      a1[r] = fminf(fminf(s2, s3), a1[r]);
    }
  }

  #pragma unroll
  for (int r = 0; r < TROWS; ++r) {
    float s = fminf(a0[r], a1[r]);
    float d2 = fmaf(2.0f, s, p2[r]);         // ||p||^2 + ||y||^2 - 2 p.y
    d2 = fmaxf(d2, 0.0f);                    // same as per-pair clamp (monotone)
    // d2 >= 0 -> IEEE bits monotone as unsigned.
    atomicMin(minbase + t + r * TPB, __float_as_uint(d2));
  }
}

__global__ __launch_bounds__(TPB) void reduce_kernel(float* __restrict__ out) {
  const int total = 2 * Bc * Nc;
  float s = 0.0f;
  for (int i = blockIdx.x * TPB + threadIdx.x; i < total; i += gridDim.x * TPB)
    s += __uint_as_float(g_mins[i]);
  #pragma unroll
  for (int off = 32; off > 0; off >>= 1) s += __shfl_down(s, off, 64);
  __shared__ float wsum[TPB / 64];
  const int lane = threadIdx.x & 63;
  const int wid  = threadIdx.x >> 6;
  if (lane == 0) wsum[wid] = s;
  __syncthreads();
  if (threadIdx.x == 0) {
    float tot = 0.0f;
    #pragma unroll
    for (int w = 0; w < TPB / 64; ++w) tot += wsum[w];
    atomicAdd(out, tot * (1.0f / (float)(Bc * Nc)));
  }
}

extern "C" void kernel_launch(void* const* d_in, const int* in_sizes, int n_in,
                              void* d_out, int out_size, void* d_ws, size_t ws_size,
                              hipStream_t stream) {
  const float* pred = (const float*)d_in[0];
  const float* gt   = (const float*)d_in[1];
  float* out = (float*)d_out;

  init_kernel<<<(2 * Bc * Nc + TPB - 1) / TPB, TPB, 0, stream>>>(out);

  dim3 grid(NRB * NJCH, Bc, 2);   // 64 x 8 x 2 = 1024 blocks
  cham_kernel<<<grid, TPB, 0, stream>>>(pred, gt);

  reduce_kernel<<<64, TPB, 0, stream>>>(out);
}